// Round 3
// baseline (542.796 us; speedup 1.0000x reference)
//
#include <hip/hip_runtime.h>

// Problem constants
constexpr int H = 128, W = 128;
constexpr int IMG = H * W;        // 16384
constexpr int STRIP = 32;         // rows per 32-lane unit
constexpr int STRIPS = H / STRIP; // 4
constexpr int UNITS_PER_BLOCK = 8; // 256 threads = 8 x 32-lane units

__device__ __forceinline__ float max3f(float a, float b, float c) {
    return fmaxf(fmaxf(a, b), c);  // -> v_max3_f32
}
// hw transcendentals: v_exp_f32 = 2^x, v_log_f32 = log2(x)
__device__ __forceinline__ float exp2_hw(float x) { return __builtin_amdgcn_exp2f(x); }
__device__ __forceinline__ float log2_hw(float x) { return __builtin_amdgcn_logf(x); }
__device__ __forceinline__ float rcp_hw(float x)  { return __builtin_amdgcn_rcpf(x); }

// One 32-lane group = one (image, 32-row strip). No LDS tile, no barrier.
// Rolling 3-row landmark window in registers (float4/lane = 4 columns),
// horizontal halo via 2 width-32 shuffles.
//
// KEY CHANGE (r3): prefetch DISTANCE 2. lmk uses a 5-register rotation,
// pred a 3-register rotation; the rows consumed at step k were issued at
// step k-2, so the per-step vmcnt wait tolerates the 4 newer in-flight
// loads. Distance-1 prefetch (r2) exposed HBM latency -> VALUBusy 30%.
// Loop is fully unrolled => all rotation indices are compile-time
// constants => arrays live in registers (no scratch).
//
// Loss math (verified absmax=0 in rounds 1-2): both branches share the
// form alpha*log2(1+2^beta)+gamma -> select beta BEFORE transcendentals:
//   lo = 9.70406*log2(1 + 2^(asl*log2 d))
//   hi = A*(d-0.5) + 9.70406*log2(1 + 2^(-asl)), A = 28*asl*E*rcp(1+E)
// Row/col replicate-clamp == -inf pad of lax.reduce_window under max.
__global__ __launch_bounds__(256, 8) void awing_partial(
    const float* __restrict__ pred,
    const float* __restrict__ lmk,
    float* __restrict__ part)
{
    __shared__ float wsum[4];

    const int tid  = threadIdx.x;
    const int lane = tid & 31;                            // float4 column
    const int unit = blockIdx.x * UNITS_PER_BLOCK + (tid >> 5);
    const int img  = unit >> 2;                           // STRIPS == 4
    const int st   = unit & 3;
    const int row0 = st * STRIP;
    const float4* l4 = (const float4*)(lmk  + (size_t)img * IMG) + lane;
    const float4* p4 = (const float4*)(pred + (size_t)img * IMG) + lane;
    // row r -> l4[r*32]

    const bool le = (lane == 0), re = (lane == 31);

    // Pipeline state: L[] holds lmk rows, P[] holds pred rows.
    // At step k (global row r = row0+k):
    //   window = L[k%5] (r-1), L[(k+1)%5] (r), L[(k+2)%5] (r+1); pred = P[k%3]
    //   prefetch L[(k+4)%5] <- lmk row r+3, P[(k+2)%3] <- pred row r+2
    float4 L[5], P[3];
    L[0] = l4[max(row0 - 1, 0) * 32];
    L[1] = l4[(row0 + 0) * 32];
    L[2] = l4[(row0 + 1) * 32];
    L[3] = l4[(row0 + 2) * 32];
    P[0] = p4[(row0 + 0) * 32];
    P[1] = p4[(row0 + 1) * 32];

    float acc = 0.0f;

#pragma unroll
    for (int k = 0; k < STRIP; ++k) {
        const int r = row0 + k;
        // depth-2 prefetch (rows clamped; overflow rows are L2-warm
        // neighbor-strip data, negligible traffic)
        L[(k + 4) % 5] = l4[min(r + 3, H - 1) * 32];
        P[(k + 2) % 3] = p4[min(r + 2, H - 1) * 32];

        const float4 Ar = L[k % 5];
        const float4 Br = L[(k + 1) % 5];
        const float4 Cr = L[(k + 2) % 5];
        const float4 Pr = P[k % 3];

        float v0 = max3f(Ar.x, Br.x, Cr.x);
        float v1 = max3f(Ar.y, Br.y, Cr.y);
        float v2 = max3f(Ar.z, Br.z, Cr.z);
        float v3 = max3f(Ar.w, Br.w, Cr.w);
        float vL = __shfl_up(v3, 1, 32);
        float vR = __shfl_down(v0, 1, 32);
        vL = le ? v0 : vL;   // replicate-clamp == -inf pad under max
        vR = re ? v3 : vR;

        const float mm[4] = { max3f(vL, v0, v1), max3f(v0, v1, v2),
                              max3f(v1, v2, v3), max3f(v2, v3, vR) };
        const float yy[4] = { Br.x, Br.y, Br.z, Br.w };
        const float pp[4] = { Pr.x, Pr.y, Pr.z, Pr.w };

#pragma unroll
        for (int j = 0; j < 4; ++j) {
            float y    = yy[j];
            float d    = fabsf(pp[j] - y);
            float asl  = 2.1f - y;              // in (1.1, 2.1]
            bool  lo   = d < 0.5f;
            float Lg   = log2_hw(d);            // d==0 -> -inf -> E=0 (ok)
            float beta = lo ? asl * Lg : -asl;
            float E    = exp2_hw(beta);
            float S    = 1.0f + E;
            float G    = log2_hw(S);
            float Aw   = 28.0f * asl * E * rcp_hw(S);  // T2 = 2*T1 exact
            float Asel = lo ? 0.0f : Aw;
            float lossv = fmaf(Asel, d - 0.5f, 9.704060527839234f * G);
            // weight: rne(z)>=25.6 <=> z>=25.5 (round-half-even), z=255*max3x3
            float wgt  = (mm[j] * 255.0f >= 25.5f) ? 11.0f : 1.0f;
            acc = fmaf(lossv, wgt, acc);
        }
    }

    // block reduction: wave64 shuffle then 4 partials in LDS
#pragma unroll
    for (int off = 32; off > 0; off >>= 1) acc += __shfl_down(acc, off, 64);
    if ((tid & 63) == 0) wsum[tid >> 6] = acc;
    __syncthreads();
    if (tid == 0) part[blockIdx.x] = (wsum[0] + wsum[1]) + (wsum[2] + wsum[3]);
}

__global__ void final_reduce(const float* __restrict__ part, int n,
                             float* __restrict__ out, double inv_total)
{
    __shared__ double sd[4];
    int tid = threadIdx.x;
    double a = 0.0;
    for (int i = tid; i < n; i += 256) a += (double)part[i];
#pragma unroll
    for (int off = 32; off > 0; off >>= 1) a += __shfl_down(a, off, 64);
    if ((tid & 63) == 0) sd[tid >> 6] = a;
    __syncthreads();
    if (tid == 0) out[0] = (float)((sd[0] + sd[1] + sd[2] + sd[3]) * inv_total);
}

extern "C" void kernel_launch(void* const* d_in, const int* in_sizes, int n_in,
                              void* d_out, int out_size, void* d_ws, size_t ws_size,
                              hipStream_t stream)
{
    const float* pred = (const float*)d_in[0];
    const float* lmk  = (const float*)d_in[1];
    float* part = (float*)d_ws;
    int total   = in_sizes[0];            // 71303168
    int nimg    = total / IMG;            // 4352
    int nunits  = nimg * STRIPS;          // 17408
    int nblocks = nunits / UNITS_PER_BLOCK; // 2176

    awing_partial<<<nblocks, 256, 0, stream>>>(pred, lmk, part);
    final_reduce<<<1, 256, 0, stream>>>(part, nblocks, (float*)d_out,
                                        1.0 / (double)total);
}